// Round 9
// baseline (115.436 us; speedup 1.0000x reference)
//
#include <hip/hip_runtime.h>

#define IMG_H 512
#define IMG_W 512
#define N_IMG 32
#define ROWS  16                   // output rows per wave-band
#define NPIX  (32.0f * 512.0f * 512.0f)

// Load 8 consecutive cols of I and normalized T from row r (zeros outside image).
__device__ __forceinline__ void load_row8(const float* __restrict__ ip,
                                          const float* __restrict__ tp,
                                          int r, int c0, float* I, float* T) {
    if ((unsigned)r < (unsigned)IMG_H) {           // wave-uniform branch
        const float* irow = ip + (ptrdiff_t)r * IMG_W + c0;
        const float* trow = tp + (ptrdiff_t)r * IMG_W + c0;
        float4 a = *(const float4*)(irow);
        float4 b = *(const float4*)(irow + 4);
        float4 c = *(const float4*)(trow);
        float4 d = *(const float4*)(trow + 4);
        I[0]=a.x; I[1]=a.y; I[2]=a.z; I[3]=a.w;
        I[4]=b.x; I[5]=b.y; I[6]=b.z; I[7]=b.w;
        T[0]=fmaf(c.x,0.5f,0.5f); T[1]=fmaf(c.y,0.5f,0.5f);
        T[2]=fmaf(c.z,0.5f,0.5f); T[3]=fmaf(c.w,0.5f,0.5f);
        T[4]=fmaf(d.x,0.5f,0.5f); T[5]=fmaf(d.y,0.5f,0.5f);
        T[6]=fmaf(d.z,0.5f,0.5f); T[7]=fmaf(d.w,0.5f,0.5f);
    } else {
        #pragma unroll
        for (int j = 0; j < 8; ++j) { I[j] = 0.0f; T[j] = 0.0f; }
    }
}

__device__ __forceinline__ void accum(float V[5][8], const float* I, const float* T) {
    #pragma unroll
    for (int j = 0; j < 8; ++j) {
        V[0][j] += I[j];
        V[1][j] += T[j];
        V[2][j] = fmaf(I[j], I[j], V[2][j]);
        V[3][j] = fmaf(T[j], T[j], V[3][j]);
        V[4][j] = fmaf(I[j], T[j], V[4][j]);
    }
}

__device__ __forceinline__ void slide(float V[5][8], const float* hI, const float* hT,
                                      const float* lI, const float* lT) {
    #pragma unroll
    for (int j = 0; j < 8; ++j) {
        float dI = hI[j] - lI[j], aI = hI[j] + lI[j];
        float dT = hT[j] - lT[j], aT = hT[j] + lT[j];
        V[0][j] += dI;
        V[1][j] += dT;
        V[2][j] = fmaf(dI, aI, V[2][j]);
        V[3][j] = fmaf(dT, aT, V[3][j]);
        V[4][j] = fmaf(hI[j], hT[j], V[4][j] - lI[j] * lT[j]);
    }
}

__device__ __forceinline__ float cc_of(float sI, float sT, float sII, float sTT, float sIT) {
    const float inv81 = 1.0f / 81.0f;
    float u     = sI * inv81;
    float w     = sT * inv81;
    float cross = fmaf(-u, sT, sIT);
    float iv    = fmaf(-u, sI, sII);
    float tv    = fmaf(-w, sT, sTT);
    float den   = fmaf(tv, iv, 1e-5f);
    return cross * cross * __builtin_amdgcn_rcpf(den);
}

// One output row: halo via wave shuffles, zero LDS, no barriers. (R7-proven)
__device__ __forceinline__ float hphase_cc(const float V[5][8], int lane) {
    float h[5][8];
    const bool l0 = (lane == 0), l63 = (lane == 63);
    #pragma unroll
    for (int a = 0; a < 5; ++a) {
        const float* o = V[a];
        float L0 = __shfl_up(o[4], 1);
        float L1 = __shfl_up(o[5], 1);
        float L2 = __shfl_up(o[6], 1);
        float L3 = __shfl_up(o[7], 1);
        float R0 = __shfl_down(o[0], 1);
        float R1 = __shfl_down(o[1], 1);
        float R2 = __shfl_down(o[2], 1);
        float R3 = __shfl_down(o[3], 1);
        if (l0)  { L0 = 0.f; L1 = 0.f; L2 = 0.f; L3 = 0.f; }
        if (l63) { R0 = 0.f; R1 = 0.f; R2 = 0.f; R3 = 0.f; }
        float s = ((L0 + L1) + (L2 + L3)) + ((o[0] + o[1]) + (o[2] + o[3])) + o[4];
        h[a][0] = s;
        s += o[5] - L0;   h[a][1] = s;
        s += o[6] - L1;   h[a][2] = s;
        s += o[7] - L2;   h[a][3] = s;
        s += R0   - L3;   h[a][4] = s;
        s += R1   - o[0]; h[a][5] = s;
        s += R2   - o[1]; h[a][6] = s;
        s += R3   - o[2]; h[a][7] = s;
    }
    float acc = 0.0f;
    #pragma unroll
    for (int j = 0; j < 8; ++j)
        acc += cc_of(h[0][j], h[1][j], h[2][j], h[3][j], h[4][j]);
    return acc;
}

__global__ __launch_bounds__(256)
void cc_loss_kernel(const float* __restrict__ in, const float* __restrict__ tg,
                    float* __restrict__ out) {
    __shared__ float red[4];

    const int t    = threadIdx.x;
    const int w    = t >> 6;
    const int lane = t & 63;

    // 1024 wave-tasks: 32 images x 32 bands of 16 rows. XCD slab swizzle.
    const int slab  = blockIdx.x & 7;           // 256 blocks: 8 slabs x 32
    const int idx   = blockIdx.x >> 3;          // 0..31
    const int gtask = slab * 128 + idx * 4 + w; // 0..1023
    const int img   = gtask >> 5;               // 32 bands per image
    const int band  = gtask & 31;
    const int rA    = band * ROWS;              // output rows rA..rA+15
    const int c0    = lane * 8;

    const size_t base = (size_t)img * (IMG_H * IMG_W);
    const float* ip = in + base;
    const float* tp = tg + base;

    float V[5][8] = {{0.f}};
    float acc = 0.0f;

    // ---- warm-up: rows rA-4 .. rA+4 ----
    {
        float I[8], T[8];
        #pragma unroll
        for (int k = 0; k < 9; ++k) {
            load_row8(ip, tp, rA - 4 + k, c0, I, T);
            accum(V, I, T);
        }
    }

    // ---- ring slots: slide s consumes enter row rA+4+s / trail row rA-5+s.
    //      slot (s-1)&1; each slot refilled 2 slides ahead. ----
    float E0I[8], E0T[8], L0I[8], L0T[8];       // slot 0: odd slides
    float E1I[8], E1T[8], L1I[8], L1T[8];       // slot 1: even slides
    load_row8(ip, tp, rA + 5, c0, E0I, E0T);    // s=1 enter
    load_row8(ip, tp, rA - 4, c0, L0I, L0T);    // s=1 trail
    load_row8(ip, tp, rA + 6, c0, E1I, E1T);    // s=2 enter
    load_row8(ip, tp, rA - 3, c0, L1I, L1T);    // s=2 trail

    acc += hphase_cc(V, lane);                  // output row rA

    // ---- pair loop: slides s = 2p+1, 2p+2 for p = 0..5 (slides 1..12) ----
    for (int p = 0; p < 6; ++p) {
        const int s0 = 2 * p + 1;
        // slide s0 (slot 0), refill slot 0 for slide s0+2
        slide(V, E0I, E0T, L0I, L0T);
        load_row8(ip, tp, rA + 6 + s0, c0, E0I, E0T);
        load_row8(ip, tp, rA - 3 + s0, c0, L0I, L0T);
        acc += hphase_cc(V, lane);              // row rA+s0
        // slide s0+1 (slot 1), refill slot 1 for slide s0+3
        slide(V, E1I, E1T, L1I, L1T);
        load_row8(ip, tp, rA + 7 + s0, c0, E1I, E1T);
        load_row8(ip, tp, rA - 2 + s0, c0, L1I, L1T);
        acc += hphase_cc(V, lane);              // row rA+s0+1
    }

    // ---- tail: slides 13 (slot0, refill for 15), 14 (slot1), 15 (slot0) ----
    slide(V, E0I, E0T, L0I, L0T);               // s=13
    load_row8(ip, tp, rA + 19, c0, E0I, E0T);
    load_row8(ip, tp, rA + 10, c0, L0I, L0T);
    acc += hphase_cc(V, lane);                  // row rA+13
    slide(V, E1I, E1T, L1I, L1T);               // s=14
    acc += hphase_cc(V, lane);                  // row rA+14
    slide(V, E0I, E0T, L0I, L0T);               // s=15
    acc += hphase_cc(V, lane);                  // row rA+15

    // ---- reduction: wave shuffle, one block barrier, one atomic ----
    #pragma unroll
    for (int off = 32; off > 0; off >>= 1) acc += __shfl_down(acc, off);
    if (lane == 0) red[w] = acc;
    __syncthreads();
    if (t == 0)
        atomicAdd(out, (red[0] + red[1] + red[2] + red[3]) * (-1.0f / NPIX));
}

extern "C" void kernel_launch(void* const* d_in, const int* in_sizes, int n_in,
                              void* d_out, int out_size, void* d_ws, size_t ws_size,
                              hipStream_t stream) {
    const float* in = (const float*)d_in[0];
    const float* tg = (const float*)d_in[1];
    float* out = (float*)d_out;

    hipMemsetAsync(out, 0, sizeof(float), stream);
    dim3 grid(256);                             // 1024 wave-bands / 4 waves per block
    cc_loss_kernel<<<grid, 256, 0, stream>>>(in, tg, out);
}

// Round 10
// 112.128 us; speedup vs baseline: 1.0295x; 1.0295x over previous
//
#include <hip/hip_runtime.h>

#define IMG_H 512
#define IMG_W 512
#define N_IMG 32
#define ROWS  8                    // output rows per wave-band
#define NPIX  (32.0f * 512.0f * 512.0f)

// Load 16 cols (own 8 + 4 halo each side) of I and normalized T from row r.
// Zero-fills outside the image (rows and side halos). No cross-lane ops.
__device__ __forceinline__ void load_row16(const float* __restrict__ ip,
                                           const float* __restrict__ tp,
                                           int r, int c0, bool l0, bool l63,
                                           float* I, float* T) {
    if ((unsigned)r < (unsigned)IMG_H) {           // wave-uniform branch
        const float* irow = ip + (ptrdiff_t)r * IMG_W;
        const float* trow = tp + (ptrdiff_t)r * IMG_W;
        const int cl = l0  ? 0   : c0 - 4;         // clamped (values masked below)
        const int cr = l63 ? 508 : c0 + 8;
        float4 a0 = *(const float4*)(irow + cl);
        float4 a1 = *(const float4*)(irow + c0);
        float4 a2 = *(const float4*)(irow + c0 + 4);
        float4 a3 = *(const float4*)(irow + cr);
        float4 b0 = *(const float4*)(trow + cl);
        float4 b1 = *(const float4*)(trow + c0);
        float4 b2 = *(const float4*)(trow + c0 + 4);
        float4 b3 = *(const float4*)(trow + cr);
        if (l0)  { a0 = make_float4(0.f,0.f,0.f,0.f); b0 = a0; }
        if (l63) { a3 = make_float4(0.f,0.f,0.f,0.f); b3 = a3; }
        I[0]=a0.x;  I[1]=a0.y;  I[2]=a0.z;  I[3]=a0.w;
        I[4]=a1.x;  I[5]=a1.y;  I[6]=a1.z;  I[7]=a1.w;
        I[8]=a2.x;  I[9]=a2.y;  I[10]=a2.z; I[11]=a2.w;
        I[12]=a3.x; I[13]=a3.y; I[14]=a3.z; I[15]=a3.w;
        T[0]=fmaf(b0.x,0.5f,0.5f);  T[1]=fmaf(b0.y,0.5f,0.5f);
        T[2]=fmaf(b0.z,0.5f,0.5f);  T[3]=fmaf(b0.w,0.5f,0.5f);
        T[4]=fmaf(b1.x,0.5f,0.5f);  T[5]=fmaf(b1.y,0.5f,0.5f);
        T[6]=fmaf(b1.z,0.5f,0.5f);  T[7]=fmaf(b1.w,0.5f,0.5f);
        T[8]=fmaf(b2.x,0.5f,0.5f);  T[9]=fmaf(b2.y,0.5f,0.5f);
        T[10]=fmaf(b2.z,0.5f,0.5f); T[11]=fmaf(b2.w,0.5f,0.5f);
        T[12]=fmaf(b3.x,0.5f,0.5f); T[13]=fmaf(b3.y,0.5f,0.5f);
        T[14]=fmaf(b3.z,0.5f,0.5f); T[15]=fmaf(b3.w,0.5f,0.5f);
        // zero the halo values that came from clamped loads but are outside image
        if (l0)  { /* cols -4..-1 */ }   // already zeroed via a0/b0
        if (l63) { /* cols 512..515 */ } // already zeroed via a3/b3
    } else {
        #pragma unroll
        for (int j = 0; j < 16; ++j) { I[j] = 0.0f; T[j] = 0.0f; }
    }
}

__device__ __forceinline__ void accum16(float V[5][16], const float* I, const float* T) {
    #pragma unroll
    for (int j = 0; j < 16; ++j) {
        V[0][j] += I[j];
        V[1][j] += T[j];
        V[2][j] = fmaf(I[j], I[j], V[2][j]);
        V[3][j] = fmaf(T[j], T[j], V[3][j]);
        V[4][j] = fmaf(I[j], T[j], V[4][j]);
    }
}

__device__ __forceinline__ void slide16(float V[5][16], const float* hI, const float* hT,
                                        const float* lI, const float* lT) {
    #pragma unroll
    for (int j = 0; j < 16; ++j) {
        float dI = hI[j] - lI[j], aI = hI[j] + lI[j];
        float dT = hT[j] - lT[j], aT = hT[j] + lT[j];
        V[0][j] += dI;
        V[1][j] += dT;
        V[2][j] = fmaf(dI, aI, V[2][j]);
        V[3][j] = fmaf(dT, aT, V[3][j]);
        V[4][j] = fmaf(hI[j], hT[j], V[4][j] - lI[j] * lT[j]);
    }
}

__device__ __forceinline__ float cc_of(float sI, float sT, float sII, float sTT, float sIT) {
    const float inv81 = 1.0f / 81.0f;
    float u     = sI * inv81;
    float w     = sT * inv81;
    float cross = fmaf(-u, sT, sIT);
    float iv    = fmaf(-u, sI, sII);
    float tv    = fmaf(-w, sT, sTT);
    float den   = fmaf(tv, iv, 1e-5f);
    return cross * cross * __builtin_amdgcn_rcpf(den);
}

// One output row, fully in-lane: 9-tap sliding sums over the 16-col V window.
__device__ __forceinline__ float hphase_cc16(const float V[5][16]) {
    float h[5][8];
    #pragma unroll
    for (int a = 0; a < 5; ++a) {
        const float* v = V[a];
        float s = ((v[0] + v[1]) + (v[2] + v[3])) + ((v[4] + v[5]) + (v[6] + v[7])) + v[8];
        h[a][0] = s;
        s += v[9]  - v[0]; h[a][1] = s;
        s += v[10] - v[1]; h[a][2] = s;
        s += v[11] - v[2]; h[a][3] = s;
        s += v[12] - v[3]; h[a][4] = s;
        s += v[13] - v[4]; h[a][5] = s;
        s += v[14] - v[5]; h[a][6] = s;
        s += v[15] - v[6]; h[a][7] = s;
    }
    float acc = 0.0f;
    #pragma unroll
    for (int j = 0; j < 8; ++j)
        acc += cc_of(h[0][j], h[1][j], h[2][j], h[3][j], h[4][j]);
    return acc;
}

__global__ __launch_bounds__(256)
void cc_loss_kernel(const float* __restrict__ in, const float* __restrict__ tg,
                    float* __restrict__ out) {
    __shared__ float red[4];

    const int t    = threadIdx.x;
    const int w    = t >> 6;
    const int lane = t & 63;

    // 2048 wave-tasks: 32 images x 64 bands of 8 rows. XCD slab swizzle.
    const int slab  = blockIdx.x & 7;           // 512 blocks: 8 slabs x 64
    const int idx   = blockIdx.x >> 3;          // 0..63
    const int local = idx * 4 + w;              // 0..255 within slab
    const int img   = slab * 4 + (local >> 6);  // 4 images per slab
    const int band  = local & 63;
    const int rA    = band * ROWS;              // output rows rA..rA+7
    const int c0    = lane * 8;
    const bool l0   = (lane == 0), l63 = (lane == 63);

    const size_t base = (size_t)img * (IMG_H * IMG_W);
    const float* ip = in + base;
    const float* tp = tg + base;

    float V[5][16] = {{0.f}};
    float acc = 0.0f;

    // ---- warm-up: rows rA-4 .. rA+4 ----
    {
        float I[16], T[16];
        #pragma unroll 3
        for (int k = 0; k < 9; ++k) {
            load_row16(ip, tp, rA - 4 + k, c0, l0, l63, I, T);
            accum16(V, I, T);
        }
    }

    // ---- steady: 1-slide-ahead prefetch, zero DS ops ----
    float EI[16], ET[16], LI[16], LT[16];
    load_row16(ip, tp, rA + 5, c0, l0, l63, EI, ET);   // enter row for slide 1
    load_row16(ip, tp, rA - 4, c0, l0, l63, LI, LT);   // leave row for slide 1

    acc += hphase_cc16(V);                      // output row rA

    for (int j = 0; j < ROWS - 1; ++j) {        // slides 1..7
        slide16(V, EI, ET, LI, LT);
        if (j < ROWS - 2) {
            load_row16(ip, tp, rA + 6 + j, c0, l0, l63, EI, ET);
            load_row16(ip, tp, rA - 3 + j, c0, l0, l63, LI, LT);
        }
        acc += hphase_cc16(V);                  // output row rA+1+j
    }

    // ---- reduction: wave shuffle, one block barrier, one atomic ----
    #pragma unroll
    for (int off = 32; off > 0; off >>= 1) acc += __shfl_down(acc, off);
    if (lane == 0) red[w] = acc;
    __syncthreads();
    if (t == 0)
        atomicAdd(out, (red[0] + red[1] + red[2] + red[3]) * (-1.0f / NPIX));
}

extern "C" void kernel_launch(void* const* d_in, const int* in_sizes, int n_in,
                              void* d_out, int out_size, void* d_ws, size_t ws_size,
                              hipStream_t stream) {
    const float* in = (const float*)d_in[0];
    const float* tg = (const float*)d_in[1];
    float* out = (float*)d_out;

    hipMemsetAsync(out, 0, sizeof(float), stream);
    dim3 grid(512);                             // 2048 wave-bands / 4 waves per block
    cc_loss_kernel<<<grid, 256, 0, stream>>>(in, tg, out);
}